// Round 4
// baseline (149.553 us; speedup 1.0000x reference)
//
#include <hip/hip_runtime.h>
#include <hip/hip_bf16.h>
#include <stdint.h>
#include <stddef.h>

#define NTOT 8192
#define BS   4096
#define DIM  1024
#define NTRI 2080   // 64*65/2 triangular tiles

// ws layout (bytes)
#define OFF_TB      0u          // bf16 total: 8192*1024*2 = 16777216
#define OFF_SQ      16777216u   // f32 [8192]
#define OFF_COLPART 16809984u   // f32 [128][1024]
#define OFF_BWP     17334272u   // f32 [8]
#define OFF_PART    17334336u   // f32 [NTRI]

typedef __attribute__((ext_vector_type(8))) short bf16x8;
typedef __attribute__((ext_vector_type(4))) float f32x4;

__device__ __forceinline__ unsigned short f2bf_rne(float f) {
  unsigned u = __float_as_uint(f);
  u += 0x7fffu + ((u >> 16) & 1u);
  return (unsigned short)(u >> 16);
}

__device__ __forceinline__ float bf2f(unsigned short h) {
  return __uint_as_float((unsigned)h << 16);
}

__device__ __forceinline__ float fast_sqrt(float x) {
#if __has_builtin(__builtin_amdgcn_sqrtf)
  return __builtin_amdgcn_sqrtf(x);
#else
  float r; asm("v_sqrt_f32 %0, %1" : "=v"(r) : "v"(x)); return r;
#endif
}

__device__ __forceinline__ float fast_exp2(float x) {
#if __has_builtin(__builtin_amdgcn_exp2f)
  return __builtin_amdgcn_exp2f(x);
#else
  float r; asm("v_exp_f32 %0, %1" : "=v"(r) : "v"(x)); return r;
#endif
}

__device__ __forceinline__ void load_lds16(const void* g, void* l) {
  __builtin_amdgcn_global_load_lds((const __attribute__((address_space(1))) void*)g,
                                   (__attribute__((address_space(3))) void*)l,
                                   16, 0, 0);
}

// ---- kernel A: bf16 convert + row sums of squares (16 rows/block) ----
__global__ __launch_bounds__(256) void prep_kernel(const float* __restrict__ src,
                                                   const float* __restrict__ tgt,
                                                   unsigned short* __restrict__ tb,
                                                   float* __restrict__ sq) {
  const int t = threadIdx.x;
  const int lane = t & 63, wave = t >> 6;
  const int r0 = blockIdx.x * 16;
  __shared__ float rs[16][4];
#pragma unroll 4
  for (int r = 0; r < 16; ++r) {
    const int row = r0 + r;
    const float* base = (row < BS) ? (src + (size_t)row * DIM)
                                   : (tgt + (size_t)(row - BS) * DIM);
    float4 v = *reinterpret_cast<const float4*>(base + t * 4);
    ushort4 b;
    b.x = f2bf_rne(v.x); b.y = f2bf_rne(v.y);
    b.z = f2bf_rne(v.z); b.w = f2bf_rne(v.w);
    *reinterpret_cast<ushort4*>(tb + (size_t)row * DIM + t * 4) = b;
    float s = v.x*v.x + v.y*v.y + v.z*v.z + v.w*v.w;
#pragma unroll
    for (int off = 32; off > 0; off >>= 1) s += __shfl_down(s, off, 64);
    if (lane == 0) rs[r][wave] = s;
  }
  __syncthreads();
  if (t < 16) sq[r0 + t] = (rs[t][0] + rs[t][1]) + (rs[t][2] + rs[t][3]);
}

// ---- kernel B: column-sum partials from the cache-hot bf16 copy ----
__global__ __launch_bounds__(256) void colsum_kernel(const unsigned short* __restrict__ tb,
                                                     float* __restrict__ colpart) {
  const int g = blockIdx.x;   // 128 blocks, 64 rows each
  const int t = threadIdx.x;  // 4 cols per thread
  float a0 = 0.f, a1 = 0.f, a2 = 0.f, a3 = 0.f;
  for (int r = 0; r < 64; ++r) {
    const int row = g * 64 + r;
    ushort4 u = *reinterpret_cast<const ushort4*>(tb + (size_t)row * DIM + t * 4);
    a0 += bf2f(u.x); a1 += bf2f(u.y); a2 += bf2f(u.z); a3 += bf2f(u.w);
  }
  float4 o = {a0, a1, a2, a3};
  *reinterpret_cast<float4*>(colpart + (size_t)g * 1024 + t * 4) = o;
}

// ---- kernel C: bandwidth from analytic sum(L2), 1024 threads (1 col/thread) ----
__global__ __launch_bounds__(1024) void bw_kernel(const float* __restrict__ sq,
                                                  const float* __restrict__ colpart,
                                                  float* __restrict__ bwp) {
  const int t = threadIdx.x;
  double s1 = 0.0;
#pragma unroll
  for (int i = 0; i < 8; ++i) s1 += (double)sq[t + i * 1024];
  float s = 0.f;
  for (int g = 0; g < 128; ++g) s += colpart[(size_t)g * 1024 + t];
  double s2 = (double)s * (double)s;
  __shared__ double r1[1024], r2[1024];
  r1[t] = s1; r2[t] = s2;
  __syncthreads();
  for (int off = 512; off > 0; off >>= 1) {
    if (t < off) { r1[t] += r1[t + off]; r2[t] += r2[t + off]; }
    __syncthreads();
  }
  if (t == 0) {
    const double n = (double)NTOT;
    double sumL2 = 2.0 * n * r1[0] - 2.0 * r2[0];
    double bw = sumL2 / (n * n - n);
    bw = bw / 4.0;  // KERNEL_MUL^(KERNEL_NUM//2) = 2^2
    const double LOG2E = 1.4426950408889634;
    for (int k = 0; k < 5; ++k)
      bwp[k] = (float)(-LOG2E / (bw * (double)(1 << k)));  // exp2-folded
  }
}

// staging: linear LDS dest (gload_lds HW requirement), pre-swizzled global
// source so data lands in XOR-swizzled layout. chunk f (16B) holds row f>>2,
// col-chunk (f&3)^((f>>3)&3)  [byte bits 5:4 ^= bits 8:7 — involution].
__device__ __forceinline__ void stage_tile(const short* __restrict__ T, size_t rowbase,
                                           int k0, short* lds, int tid, int wave) {
  const int f0 = tid, f1 = 256 + tid;
  load_lds16(T + (rowbase + (f0 >> 2)) * DIM + k0 + (((f0 & 3) ^ ((f0 >> 3) & 3)) * 8),
             lds + (size_t)(wave * 64) * 8);
  load_lds16(T + (rowbase + (f1 >> 2)) * DIM + k0 + (((f1 & 3) ^ ((f1 >> 3) & 3)) * 8),
             lds + (size_t)(256 + wave * 64) * 8);
}

// ---- kernel D: fused bf16 Gram GEMM + RBF epilogue, upper-triangular tiles ----
// 128x128 tile, BK=32, 4 waves (2x2), double-buffered LDS (T3-minimum 2-phase):
// issue next-tile staging BEFORE ds_read/MFMA of current tile; one barrier/iter
// (__syncthreads emits vmcnt(0)+lgkmcnt(0) drain + s_barrier). ds_read uses the
// XOR-swizzled address matching the staged layout -> 2-way bank alias (free).
__global__ __launch_bounds__(256) void mmd_gemm(const short* __restrict__ T,
                                                const float* __restrict__ sq,
                                                const float* __restrict__ bwp,
                                                float* __restrict__ partials) {
  __shared__ __align__(16) short sA[2][128 * 32];
  __shared__ __align__(16) short sB[2][128 * 32];
  __shared__ float wred[4];

  const int tid  = threadIdx.x;
  const int lane = tid & 63;
  const int wave = tid >> 6;       // 0..3
  const int wr   = wave >> 1;      // wave row (0..1)
  const int wc   = wave & 1;       // wave col (0..1)

  // XCD-aware chunked swizzle: 8 XCDs x 260 contiguous triangular tiles
  const int tno = (blockIdx.x & 7) * 260 + (blockIdx.x >> 3);
  // triangular decode: tile tno -> (bi, bj) with bi<=bj, f(bi)=bi*(129-bi)/2
  int bi = (int)((129.0f - fast_sqrt(129.0f * 129.0f - 8.0f * (float)tno)) * 0.5f);
  while (bi > 0 && bi * (129 - bi) / 2 > tno) --bi;
  while ((bi + 1) * (129 - (bi + 1)) / 2 <= tno) ++bi;
  const int bj = bi + (tno - bi * (129 - bi) / 2);

  const size_t arow = (size_t)bi * 128;
  const size_t brow = (size_t)bj * 128;

  f32x4 acc[4][4] = {};

  const int r15 = lane & 15;
  const int kg  = lane >> 4;               // 0..3
  const int kgx = kg ^ ((r15 >> 1) & 3);   // swizzled col-chunk for ds_read

  // prologue: stage K-tile 0 into buf0
  stage_tile(T, arow, 0, &sA[0][0], tid, wave);
  stage_tile(T, brow, 0, &sB[0][0], tid, wave);
  __syncthreads();

  int cur = 0;
  for (int t = 0; t < 32; ++t) {
    // phase 1: issue next tile's staging (flies under ds_read+MFMA)
    if (t < 31) {
      const int k0n = (t + 1) * 32;
      stage_tile(T, arow, k0n, &sA[cur ^ 1][0], tid, wave);
      stage_tile(T, brow, k0n, &sB[cur ^ 1][0], tid, wave);
    }
    // phase 2: ds_read current buffer (swizzled addr) + MFMA
    const short* A = &sA[cur][0];
    const short* B = &sB[cur][0];
    bf16x8 a[4], b[4];
#pragma unroll
    for (int m = 0; m < 4; ++m)
      a[m] = *reinterpret_cast<const bf16x8*>(&A[(wr * 64 + m * 16 + r15) * 32 + kgx * 8]);
#pragma unroll
    for (int n = 0; n < 4; ++n)
      b[n] = *reinterpret_cast<const bf16x8*>(&B[(wc * 64 + n * 16 + r15) * 32 + kgx * 8]);

#pragma unroll
    for (int m = 0; m < 4; ++m)
#pragma unroll
      for (int n = 0; n < 4; ++n)
        acc[m][n] = __builtin_amdgcn_mfma_f32_16x16x32_bf16(a[m], b[n], acc[m][n], 0, 0, 0);

    __syncthreads();   // vmcnt(0)+lgkmcnt(0)+s_barrier: next buf staged, cur reads done
    cur ^= 1;
  }

  // epilogue: x = l2 * ni0 (exp2-domain); e_k = sqrt(e_{k-1})
  const float ni0 = bwp[0];          // = -log2e / bw
  const float c2  = -2.f * ni0;
  const int hi = lane >> 4;

  float ai[4][4];
#pragma unroll
  for (int m = 0; m < 4; ++m)
#pragma unroll
    for (int r = 0; r < 4; ++r)
      ai[m][r] = sq[bi * 128 + wr * 64 + m * 16 + hi * 4 + r] * ni0;

  float tsum = 0.f;
#pragma unroll
  for (int n = 0; n < 4; ++n) {
    const float bjv = sq[bj * 128 + wc * 64 + n * 16 + r15] * ni0;
#pragma unroll
    for (int m = 0; m < 4; ++m) {
#pragma unroll
      for (int r = 0; r < 4; ++r) {
        float x = fmaf(acc[m][n][r], c2, ai[m][r] + bjv);
        float e0 = fast_exp2(x);      // x ~ -6, no underflow anywhere in chain
        float e1 = fast_sqrt(e0);
        float e2 = fast_sqrt(e1);
        float e3 = fast_sqrt(e2);
        float e4 = fast_sqrt(e3);
        tsum += ((e0 + e1) + (e2 + e3)) + e4;
      }
    }
  }

#pragma unroll
  for (int off = 32; off > 0; off >>= 1) tsum += __shfl_down(tsum, off, 64);
  if (lane == 0) wred[wave] = tsum;
  __syncthreads();
  if (tid == 0) {
    float sign = ((bi < 32) == (bj < 32)) ? 1.f : -1.f;
    float w    = (bi == bj) ? 1.f : 2.f;
    partials[tno] = sign * w * ((wred[0] + wred[1]) + (wred[2] + wred[3]));
  }
}

// ---- kernel E: final reduction ----
__global__ __launch_bounds__(256) void finish_kernel(const float* __restrict__ partials,
                                                     float* __restrict__ out) {
  const int t = threadIdx.x;
  double s = 0.0;
  for (int i = t; i < NTRI; i += 256) s += (double)partials[i];
  __shared__ double rd[256];
  rd[t] = s;
  __syncthreads();
  for (int off = 128; off > 0; off >>= 1) {
    if (t < off) rd[t] += rd[t + off];
    __syncthreads();
  }
  if (t == 0) out[0] = (float)(rd[0] / 16777216.0);  // / bs^2
}

extern "C" void kernel_launch(void* const* d_in, const int* in_sizes, int n_in,
                              void* d_out, int out_size, void* d_ws, size_t ws_size,
                              hipStream_t stream) {
  const float* src = (const float*)d_in[0];
  const float* tgt = (const float*)d_in[1];
  char* ws = (char*)d_ws;
  unsigned short* tb = (unsigned short*)(ws + OFF_TB);
  float* sq       = (float*)(ws + OFF_SQ);
  float* colpart  = (float*)(ws + OFF_COLPART);
  float* bwp      = (float*)(ws + OFF_BWP);
  float* partials = (float*)(ws + OFF_PART);

  prep_kernel<<<dim3(512), dim3(256), 0, stream>>>(src, tgt, tb, sq);
  colsum_kernel<<<dim3(128), dim3(256), 0, stream>>>(tb, colpart);
  bw_kernel<<<dim3(1), dim3(1024), 0, stream>>>(sq, colpart, bwp);
  mmd_gemm<<<dim3(NTRI), dim3(256), 0, stream>>>((const short*)tb, sq, bwp, partials);
  finish_kernel<<<dim3(1), dim3(256), 0, stream>>>(partials, (float*)d_out);
}

// Round 5
// 146.462 us; speedup vs baseline: 1.0211x; 1.0211x over previous
//
#include <hip/hip_runtime.h>
#include <hip/hip_bf16.h>
#include <stdint.h>
#include <stddef.h>

#define NTOT 8192
#define BS   4096
#define DIM  1024
#define NTRI 2080   // 64*65/2 triangular tiles

// ws layout (bytes)
#define OFF_TB      0u          // bf16 total: 8192*1024*2 = 16777216
#define OFF_SQ      16777216u   // f32 [8192]
#define OFF_COLPART 16809984u   // f32 [128][1024]
#define OFF_BWP     17334272u   // f32 [8]
#define OFF_PART    17334336u   // f32 [NTRI]

typedef __attribute__((ext_vector_type(8))) short bf16x8;
typedef __attribute__((ext_vector_type(4))) float f32x4;

__device__ __forceinline__ unsigned short f2bf_rne(float f) {
  unsigned u = __float_as_uint(f);
  u += 0x7fffu + ((u >> 16) & 1u);
  return (unsigned short)(u >> 16);
}

__device__ __forceinline__ float bf2f(unsigned short h) {
  return __uint_as_float((unsigned)h << 16);
}

__device__ __forceinline__ float fast_sqrt(float x) {
#if __has_builtin(__builtin_amdgcn_sqrtf)
  return __builtin_amdgcn_sqrtf(x);
#else
  float r; asm("v_sqrt_f32 %0, %1" : "=v"(r) : "v"(x)); return r;
#endif
}

__device__ __forceinline__ float fast_exp2(float x) {
#if __has_builtin(__builtin_amdgcn_exp2f)
  return __builtin_amdgcn_exp2f(x);
#else
  float r; asm("v_exp_f32 %0, %1" : "=v"(r) : "v"(x)); return r;
#endif
}

__device__ __forceinline__ void load_lds16(const void* g, void* l) {
  __builtin_amdgcn_global_load_lds((const __attribute__((address_space(1))) void*)g,
                                   (__attribute__((address_space(3))) void*)l,
                                   16, 0, 0);
}

// ---- kernel A: bf16 convert + row sums of squares (16 rows/block) ----
__global__ __launch_bounds__(256) void prep_kernel(const float* __restrict__ src,
                                                   const float* __restrict__ tgt,
                                                   unsigned short* __restrict__ tb,
                                                   float* __restrict__ sq) {
  const int t = threadIdx.x;
  const int lane = t & 63, wave = t >> 6;
  const int r0 = blockIdx.x * 16;
  __shared__ float rs[16][4];
#pragma unroll 4
  for (int r = 0; r < 16; ++r) {
    const int row = r0 + r;
    const float* base = (row < BS) ? (src + (size_t)row * DIM)
                                   : (tgt + (size_t)(row - BS) * DIM);
    float4 v = *reinterpret_cast<const float4*>(base + t * 4);
    ushort4 b;
    b.x = f2bf_rne(v.x); b.y = f2bf_rne(v.y);
    b.z = f2bf_rne(v.z); b.w = f2bf_rne(v.w);
    *reinterpret_cast<ushort4*>(tb + (size_t)row * DIM + t * 4) = b;
    float s = v.x*v.x + v.y*v.y + v.z*v.z + v.w*v.w;
#pragma unroll
    for (int off = 32; off > 0; off >>= 1) s += __shfl_down(s, off, 64);
    if (lane == 0) rs[r][wave] = s;
  }
  __syncthreads();
  if (t < 16) sq[r0 + t] = (rs[t][0] + rs[t][1]) + (rs[t][2] + rs[t][3]);
}

// ---- kernel B: column-sum partials from the cache-hot bf16 copy ----
__global__ __launch_bounds__(256) void colsum_kernel(const unsigned short* __restrict__ tb,
                                                     float* __restrict__ colpart) {
  const int g = blockIdx.x;   // 128 blocks, 64 rows each
  const int t = threadIdx.x;  // 4 cols per thread
  float a0 = 0.f, a1 = 0.f, a2 = 0.f, a3 = 0.f;
  for (int r = 0; r < 64; ++r) {
    const int row = g * 64 + r;
    ushort4 u = *reinterpret_cast<const ushort4*>(tb + (size_t)row * DIM + t * 4);
    a0 += bf2f(u.x); a1 += bf2f(u.y); a2 += bf2f(u.z); a3 += bf2f(u.w);
  }
  float4 o = {a0, a1, a2, a3};
  *reinterpret_cast<float4*>(colpart + (size_t)g * 1024 + t * 4) = o;
}

// ---- kernel C: bandwidth from analytic sum(L2), 1024 threads (1 col/thread) ----
__global__ __launch_bounds__(1024) void bw_kernel(const float* __restrict__ sq,
                                                  const float* __restrict__ colpart,
                                                  float* __restrict__ bwp) {
  const int t = threadIdx.x;
  double s1 = 0.0;
#pragma unroll
  for (int i = 0; i < 8; ++i) s1 += (double)sq[t + i * 1024];
  float s = 0.f;
  for (int g = 0; g < 128; ++g) s += colpart[(size_t)g * 1024 + t];
  double s2 = (double)s * (double)s;
  __shared__ double r1[1024], r2[1024];
  r1[t] = s1; r2[t] = s2;
  __syncthreads();
  for (int off = 512; off > 0; off >>= 1) {
    if (t < off) { r1[t] += r1[t + off]; r2[t] += r2[t + off]; }
    __syncthreads();
  }
  if (t == 0) {
    const double n = (double)NTOT;
    double sumL2 = 2.0 * n * r1[0] - 2.0 * r2[0];
    double bw = sumL2 / (n * n - n);
    bw = bw / 4.0;  // KERNEL_MUL^(KERNEL_NUM//2) = 2^2
    const double LOG2E = 1.4426950408889634;
    for (int k = 0; k < 5; ++k)
      bwp[k] = (float)(-LOG2E / (bw * (double)(1 << k)));  // exp2-folded
  }
}

// staging: linear LDS dest (gload_lds HW requirement), pre-swizzled global
// source so data lands XOR-swizzled: chunk f (16B) holds row f>>2,
// col-chunk (f&3)^((f>>3)&3)  [byte bits 5:4 ^= bits 8:7 — involution].
#define STAGE_TILE(Tb, rowbase, k0, lds)                                              \
  do {                                                                                \
    load_lds16(Tb + (rowbase + (f0 >> 2)) * DIM + (k0) +                              \
                   (((f0 & 3) ^ ((f0 >> 3) & 3)) * 8),                                \
               (lds) + (size_t)(wave * 64) * 8);                                      \
    load_lds16(Tb + (rowbase + (f1 >> 2)) * DIM + (k0) +                              \
                   (((f1 & 3) ^ ((f1 >> 3) & 3)) * 8),                                \
               (lds) + (size_t)(256 + wave * 64) * 8);                                \
  } while (0)

// compute one K=32 step from static buffers A,B (swizzled ds_read addr)
#define COMPUTE_STEP(Abuf, Bbuf)                                                      \
  do {                                                                                \
    bf16x8 a[4], b[4];                                                                \
    _Pragma("unroll")                                                                 \
    for (int m = 0; m < 4; ++m)                                                       \
      a[m] = *reinterpret_cast<const bf16x8*>(                                        \
          &(Abuf)[(wr * 64 + m * 16 + r15) * 32 + kgx * 8]);                          \
    _Pragma("unroll")                                                                 \
    for (int n = 0; n < 4; ++n)                                                       \
      b[n] = *reinterpret_cast<const bf16x8*>(                                        \
          &(Bbuf)[(wc * 64 + n * 16 + r15) * 32 + kgx * 8]);                          \
    _Pragma("unroll")                                                                 \
    for (int m = 0; m < 4; ++m)                                                       \
      _Pragma("unroll")                                                               \
      for (int n = 0; n < 4; ++n)                                                     \
        acc[m][n] = __builtin_amdgcn_mfma_f32_16x16x32_bf16(a[m], b[n], acc[m][n],    \
                                                            0, 0, 0);                 \
  } while (0)

// ---- kernel D: fused bf16 Gram GEMM + RBF epilogue, upper-triangular tiles ----
// 128x128 tile, BK=32, 4 waves (2x2). Double-buffered with STATIC buffer names
// (2x-unrolled K-loop, 1 barrier/K-step): stage of tile t+1 issued before
// compute of tile t; barrier's vmcnt(0) drain confirms the staged buffer, and
// each stage targets a buffer whose readers finished before the prior barrier.
__global__ __launch_bounds__(256) void mmd_gemm(const short* __restrict__ T,
                                                const float* __restrict__ sq,
                                                const float* __restrict__ bwp,
                                                float* __restrict__ partials) {
  __shared__ __align__(16) short sA0[128 * 32], sA1[128 * 32];
  __shared__ __align__(16) short sB0[128 * 32], sB1[128 * 32];
  __shared__ float wred[4];

  const int tid  = threadIdx.x;
  const int lane = tid & 63;
  const int wave = tid >> 6;       // 0..3
  const int wr   = wave >> 1;      // wave row (0..1)
  const int wc   = wave & 1;       // wave col (0..1)

  // XCD-aware chunked swizzle: 8 XCDs x 260 contiguous triangular tiles
  const int tno = (blockIdx.x & 7) * 260 + (blockIdx.x >> 3);
  // triangular decode: tile tno -> (bi, bj) with bi<=bj, f(bi)=bi*(129-bi)/2
  int bi = (int)((129.0f - fast_sqrt(129.0f * 129.0f - 8.0f * (float)tno)) * 0.5f);
  while (bi > 0 && bi * (129 - bi) / 2 > tno) --bi;
  while ((bi + 1) * (129 - (bi + 1)) / 2 <= tno) ++bi;
  const int bj = bi + (tno - bi * (129 - bi) / 2);

  const size_t arow = (size_t)bi * 128;
  const size_t brow = (size_t)bj * 128;
  const int f0 = tid, f1 = 256 + tid;

  f32x4 acc[4][4] = {};

  const int r15 = lane & 15;
  const int kg  = lane >> 4;               // 0..3
  const int kgx = kg ^ ((r15 >> 1) & 3);   // swizzled col-chunk for ds_read

  // prologue: stage K-tile 0 into buf0
  STAGE_TILE(T, arow, 0, sA0);
  STAGE_TILE(T, brow, 0, sB0);

  for (int t = 0; t < 16; ++t) {
    __syncthreads();                   // buf0 staged; prior buf1 readers done
    {                                  // stage odd tile 2t+1 into buf1
      const int k1 = t * 64 + 32;
      STAGE_TILE(T, arow, k1, sA1);
      STAGE_TILE(T, brow, k1, sB1);
    }
    COMPUTE_STEP(sA0, sB0);            // tile 2t
    __syncthreads();                   // buf1 staged; buf0 readers done
    if (t < 15) {                      // stage even tile 2t+2 into buf0
      const int k2 = t * 64 + 64;
      STAGE_TILE(T, arow, k2, sA0);
      STAGE_TILE(T, brow, k2, sB0);
    }
    COMPUTE_STEP(sA1, sB1);            // tile 2t+1
  }

  // epilogue: x = l2 * ni0 in exp2 domain; u = 2^(x/16);
  // sum_k exp2(x/2^k) = u + u^2 + u^4 + u^8 + u^16  (1 trans op total)
  const float s16 = bwp[0] * 0.0625f;  // -log2e/(16*bw)
  const float c2  = -2.f * s16;
  const int hi = lane >> 4;

  float ai[4][4];
#pragma unroll
  for (int m = 0; m < 4; ++m)
#pragma unroll
    for (int r = 0; r < 4; ++r)
      ai[m][r] = sq[bi * 128 + wr * 64 + m * 16 + hi * 4 + r] * s16;

  float tsum = 0.f;
#pragma unroll
  for (int n = 0; n < 4; ++n) {
    const float bjv = sq[bj * 128 + wc * 64 + n * 16 + r15] * s16;
#pragma unroll
    for (int m = 0; m < 4; ++m) {
#pragma unroll
      for (int r = 0; r < 4; ++r) {
        float x16 = fmaf(acc[m][n][r], c2, ai[m][r] + bjv);  // in [-0.9, 0]
        float u   = fast_exp2(x16);
        float u2 = u * u, u4 = u2 * u2, u8 = u4 * u4, u16 = u8 * u8;
        tsum += ((u + u2) + (u4 + u8)) + u16;
      }
    }
  }

#pragma unroll
  for (int off = 32; off > 0; off >>= 1) tsum += __shfl_down(tsum, off, 64);
  if (lane == 0) wred[wave] = tsum;
  __syncthreads();
  if (tid == 0) {
    float sign = ((bi < 32) == (bj < 32)) ? 1.f : -1.f;
    float w    = (bi == bj) ? 1.f : 2.f;
    partials[tno] = sign * w * ((wred[0] + wred[1]) + (wred[2] + wred[3]));
  }
}

// ---- kernel E: final reduction ----
__global__ __launch_bounds__(256) void finish_kernel(const float* __restrict__ partials,
                                                     float* __restrict__ out) {
  const int t = threadIdx.x;
  double s = 0.0;
  for (int i = t; i < NTRI; i += 256) s += (double)partials[i];
  __shared__ double rd[256];
  rd[t] = s;
  __syncthreads();
  for (int off = 128; off > 0; off >>= 1) {
    if (t < off) rd[t] += rd[t + off];
    __syncthreads();
  }
  if (t == 0) out[0] = (float)(rd[0] / 16777216.0);  // / bs^2
}

extern "C" void kernel_launch(void* const* d_in, const int* in_sizes, int n_in,
                              void* d_out, int out_size, void* d_ws, size_t ws_size,
                              hipStream_t stream) {
  const float* src = (const float*)d_in[0];
  const float* tgt = (const float*)d_in[1];
  char* ws = (char*)d_ws;
  unsigned short* tb = (unsigned short*)(ws + OFF_TB);
  float* sq       = (float*)(ws + OFF_SQ);
  float* colpart  = (float*)(ws + OFF_COLPART);
  float* bwp      = (float*)(ws + OFF_BWP);
  float* partials = (float*)(ws + OFF_PART);

  prep_kernel<<<dim3(512), dim3(256), 0, stream>>>(src, tgt, tb, sq);
  colsum_kernel<<<dim3(128), dim3(256), 0, stream>>>(tb, colpart);
  bw_kernel<<<dim3(1), dim3(1024), 0, stream>>>(sq, colpart, bwp);
  mmd_gemm<<<dim3(NTRI), dim3(256), 0, stream>>>((const short*)tb, sq, bwp, partials);
  finish_kernel<<<dim3(1), dim3(256), 0, stream>>>(partials, (float*)d_out);
}

// Round 6
// 135.458 us; speedup vs baseline: 1.1041x; 1.0812x over previous
//
#include <hip/hip_runtime.h>
#include <hip/hip_bf16.h>
#include <stdint.h>
#include <stddef.h>

#define NTOT 8192
#define BS   4096
#define DIM  1024
#define NTRI 2080   // 64*65/2 triangular tiles

// ws layout (bytes)
#define OFF_TB      0u          // bf16 total: 8192*1024*2 = 16777216
#define OFF_SQ      16777216u   // f32 [8192]
#define OFF_COLPART 16809984u   // f32 [128][1024]
#define OFF_BWP     17334272u   // f32 [8]
#define OFF_PART    17334336u   // f32 [NTRI]

typedef __attribute__((ext_vector_type(8))) short bf16x8;
typedef __attribute__((ext_vector_type(4))) float f32x4;

__device__ __forceinline__ unsigned short f2bf_rne(float f) {
  unsigned u = __float_as_uint(f);
  u += 0x7fffu + ((u >> 16) & 1u);
  return (unsigned short)(u >> 16);
}

__device__ __forceinline__ float bf2f(unsigned short h) {
  return __uint_as_float((unsigned)h << 16);
}

__device__ __forceinline__ float fast_sqrt(float x) {
#if __has_builtin(__builtin_amdgcn_sqrtf)
  return __builtin_amdgcn_sqrtf(x);
#else
  float r; asm("v_sqrt_f32 %0, %1" : "=v"(r) : "v"(x)); return r;
#endif
}

__device__ __forceinline__ float fast_exp2(float x) {
#if __has_builtin(__builtin_amdgcn_exp2f)
  return __builtin_amdgcn_exp2f(x);
#else
  float r; asm("v_exp_f32 %0, %1" : "=v"(r) : "v"(x)); return r;
#endif
}

__device__ __forceinline__ void load_lds16(const void* g, void* l) {
  __builtin_amdgcn_global_load_lds((const __attribute__((address_space(1))) void*)g,
                                   (__attribute__((address_space(3))) void*)l,
                                   16, 0, 0);
}

// ---- kernel A: bf16 convert + row sums of squares (16 rows/block) ----
__global__ __launch_bounds__(256) void prep_kernel(const float* __restrict__ src,
                                                   const float* __restrict__ tgt,
                                                   unsigned short* __restrict__ tb,
                                                   float* __restrict__ sq) {
  const int t = threadIdx.x;
  const int lane = t & 63, wave = t >> 6;
  const int r0 = blockIdx.x * 16;
  __shared__ float rs[16][4];
#pragma unroll 4
  for (int r = 0; r < 16; ++r) {
    const int row = r0 + r;
    const float* base = (row < BS) ? (src + (size_t)row * DIM)
                                   : (tgt + (size_t)(row - BS) * DIM);
    float4 v = *reinterpret_cast<const float4*>(base + t * 4);
    ushort4 b;
    b.x = f2bf_rne(v.x); b.y = f2bf_rne(v.y);
    b.z = f2bf_rne(v.z); b.w = f2bf_rne(v.w);
    *reinterpret_cast<ushort4*>(tb + (size_t)row * DIM + t * 4) = b;
    float s = v.x*v.x + v.y*v.y + v.z*v.z + v.w*v.w;
#pragma unroll
    for (int off = 32; off > 0; off >>= 1) s += __shfl_down(s, off, 64);
    if (lane == 0) rs[r][wave] = s;
  }
  __syncthreads();
  if (t < 16) sq[r0 + t] = (rs[t][0] + rs[t][1]) + (rs[t][2] + rs[t][3]);
}

// ---- kernel B: column-sum partials from the cache-hot bf16 copy ----
__global__ __launch_bounds__(256) void colsum_kernel(const unsigned short* __restrict__ tb,
                                                     float* __restrict__ colpart) {
  const int g = blockIdx.x;   // 128 blocks, 64 rows each
  const int t = threadIdx.x;  // 4 cols per thread
  float a0 = 0.f, a1 = 0.f, a2 = 0.f, a3 = 0.f;
  for (int r = 0; r < 64; ++r) {
    const int row = g * 64 + r;
    ushort4 u = *reinterpret_cast<const ushort4*>(tb + (size_t)row * DIM + t * 4);
    a0 += bf2f(u.x); a1 += bf2f(u.y); a2 += bf2f(u.z); a3 += bf2f(u.w);
  }
  float4 o = {a0, a1, a2, a3};
  *reinterpret_cast<float4*>(colpart + (size_t)g * 1024 + t * 4) = o;
}

// ---- kernel C: bandwidth from analytic sum(L2), 1024 threads (1 col/thread) ----
__global__ __launch_bounds__(1024) void bw_kernel(const float* __restrict__ sq,
                                                  const float* __restrict__ colpart,
                                                  float* __restrict__ bwp) {
  const int t = threadIdx.x;
  double s1 = 0.0;
#pragma unroll
  for (int i = 0; i < 8; ++i) s1 += (double)sq[t + i * 1024];
  float s = 0.f;
  for (int g = 0; g < 128; ++g) s += colpart[(size_t)g * 1024 + t];
  double s2 = (double)s * (double)s;
  __shared__ double r1[1024], r2[1024];
  r1[t] = s1; r2[t] = s2;
  __syncthreads();
  for (int off = 512; off > 0; off >>= 1) {
    if (t < off) { r1[t] += r1[t + off]; r2[t] += r2[t + off]; }
    __syncthreads();
  }
  if (t == 0) {
    const double n = (double)NTOT;
    double sumL2 = 2.0 * n * r1[0] - 2.0 * r2[0];
    double bw = sumL2 / (n * n - n);
    bw = bw / 4.0;  // KERNEL_MUL^(KERNEL_NUM//2) = 2^2
    const double LOG2E = 1.4426950408889634;
    for (int k = 0; k < 5; ++k)
      bwp[k] = (float)(-LOG2E / (bw * (double)(1 << k)));  // exp2-folded
  }
}

// ---- kernel D: fused bf16 Gram GEMM + RBF epilogue, upper-triangular tiles ----
// 128x128 tile, BK=32, TWO waves per block (each wave computes 128x64 via
// a[8] x b[4] frags -> 32 MFMA per wave per K-step, 24KB LDS-read per block
// per K-step vs 32KB for the 4-wave layout). Single-buffered (R3 mechanism:
// 4 blocks/CU cross-block TLP hides staging; dbuf measured slower twice).
// XOR-swizzled LDS (verified 0 conflicts), 1-trans epilogue.
__global__ __launch_bounds__(128, 2) void mmd_gemm(const short* __restrict__ T,
                                                   const float* __restrict__ sq,
                                                   const float* __restrict__ bwp,
                                                   float* __restrict__ partials) {
  __shared__ __align__(16) short sA[128 * 32];
  __shared__ __align__(16) short sB[128 * 32];
  __shared__ float wred[2];

  const int tid  = threadIdx.x;   // 0..127
  const int lane = tid & 63;
  const int w    = tid >> 6;      // wave 0/1 = output column half

  // XCD-aware chunked swizzle: 8 XCDs x 260 contiguous triangular tiles
  const int tno = (blockIdx.x & 7) * 260 + (blockIdx.x >> 3);
  // triangular decode: tile tno -> (bi, bj) with bi<=bj, f(bi)=bi*(129-bi)/2
  int bi = (int)((129.0f - fast_sqrt(129.0f * 129.0f - 8.0f * (float)tno)) * 0.5f);
  while (bi > 0 && bi * (129 - bi) / 2 > tno) --bi;
  while ((bi + 1) * (129 - (bi + 1)) / 2 <= tno) ++bi;
  const int bj = bi + (tno - bi * (129 - bi) / 2);

  const size_t arow = (size_t)bi * 128;
  const size_t brow = (size_t)bj * 128;

  f32x4 acc[8][4] = {};

  const int r15 = lane & 15;
  const int kg  = lane >> 4;               // 0..3
  const int kgx = kg ^ ((r15 >> 1) & 3);   // swizzled col-chunk for ds_read

  for (int k0 = 0; k0 < DIM; k0 += 32) {
    // stage A,B tiles (128 rows x 32 k each): 512 chunks of 16B per tile,
    // 4 gload_lds per thread per tile; linear LDS dest, pre-swizzled source
    // (chunk f: row=f>>2, src col-chunk=(f&3)^((f>>3)&3) — involution).
#pragma unroll
    for (int l = 0; l < 4; ++l) {
      const int f = l * 128 + tid;
      const int cs = ((f & 3) ^ ((f >> 3) & 3)) * 8;
      load_lds16(T + (arow + (f >> 2)) * DIM + k0 + cs,
                 &sA[(size_t)(l * 128 + w * 64) * 8]);
      load_lds16(T + (brow + (f >> 2)) * DIM + k0 + cs,
                 &sB[(size_t)(l * 128 + w * 64) * 8]);
    }
    __syncthreads();

    bf16x8 a[8], b[4];
#pragma unroll
    for (int m = 0; m < 8; ++m)
      a[m] = *reinterpret_cast<const bf16x8*>(&sA[(m * 16 + r15) * 32 + kgx * 8]);
#pragma unroll
    for (int n = 0; n < 4; ++n)
      b[n] = *reinterpret_cast<const bf16x8*>(&sB[(w * 64 + n * 16 + r15) * 32 + kgx * 8]);

    __builtin_amdgcn_s_setprio(1);
#pragma unroll
    for (int m = 0; m < 8; ++m)
#pragma unroll
      for (int n = 0; n < 4; ++n)
        acc[m][n] = __builtin_amdgcn_mfma_f32_16x16x32_bf16(a[m], b[n], acc[m][n], 0, 0, 0);
    __builtin_amdgcn_s_setprio(0);

    __syncthreads();
  }

  // epilogue: x = l2 * ni0 in exp2 domain; u = 2^(x/16);
  // sum_k exp2(x/2^k) = u + u^2 + u^4 + u^8 + u^16  (1 trans op total)
  const float s16 = bwp[0] * 0.0625f;  // -log2e/(16*bw)
  const float c2  = -2.f * s16;
  const int hi = lane >> 4;

  float ai[8][4];
#pragma unroll
  for (int m = 0; m < 8; ++m)
#pragma unroll
    for (int r = 0; r < 4; ++r)
      ai[m][r] = sq[bi * 128 + m * 16 + hi * 4 + r] * s16;

  float tsum = 0.f;
#pragma unroll
  for (int n = 0; n < 4; ++n) {
    const float bjv = sq[bj * 128 + w * 64 + n * 16 + r15] * s16;
#pragma unroll
    for (int m = 0; m < 8; ++m) {
#pragma unroll
      for (int r = 0; r < 4; ++r) {
        float x16 = fmaf(acc[m][n][r], c2, ai[m][r] + bjv);  // in [-0.9, 0]
        float u   = fast_exp2(x16);
        float u2 = u * u, u4 = u2 * u2, u8 = u4 * u4, u16 = u8 * u8;
        tsum += ((u + u2) + (u4 + u8)) + u16;
      }
    }
  }

#pragma unroll
  for (int off = 32; off > 0; off >>= 1) tsum += __shfl_down(tsum, off, 64);
  if (lane == 0) wred[w] = tsum;
  __syncthreads();
  if (tid == 0) {
    float sign = ((bi < 32) == (bj < 32)) ? 1.f : -1.f;
    float wgt  = (bi == bj) ? 1.f : 2.f;
    partials[tno] = sign * wgt * (wred[0] + wred[1]);
  }
}

// ---- kernel E: final reduction ----
__global__ __launch_bounds__(256) void finish_kernel(const float* __restrict__ partials,
                                                     float* __restrict__ out) {
  const int t = threadIdx.x;
  double s = 0.0;
  for (int i = t; i < NTRI; i += 256) s += (double)partials[i];
  __shared__ double rd[256];
  rd[t] = s;
  __syncthreads();
  for (int off = 128; off > 0; off >>= 1) {
    if (t < off) rd[t] += rd[t + off];
    __syncthreads();
  }
  if (t == 0) out[0] = (float)(rd[0] / 16777216.0);  // / bs^2
}

extern "C" void kernel_launch(void* const* d_in, const int* in_sizes, int n_in,
                              void* d_out, int out_size, void* d_ws, size_t ws_size,
                              hipStream_t stream) {
  const float* src = (const float*)d_in[0];
  const float* tgt = (const float*)d_in[1];
  char* ws = (char*)d_ws;
  unsigned short* tb = (unsigned short*)(ws + OFF_TB);
  float* sq       = (float*)(ws + OFF_SQ);
  float* colpart  = (float*)(ws + OFF_COLPART);
  float* bwp      = (float*)(ws + OFF_BWP);
  float* partials = (float*)(ws + OFF_PART);

  prep_kernel<<<dim3(512), dim3(256), 0, stream>>>(src, tgt, tb, sq);
  colsum_kernel<<<dim3(128), dim3(256), 0, stream>>>(tb, colpart);
  bw_kernel<<<dim3(1), dim3(1024), 0, stream>>>(sq, colpart, bwp);
  mmd_gemm<<<dim3(NTRI), dim3(128), 0, stream>>>((const short*)tb, sq, bwp, partials);
  finish_kernel<<<dim3(1), dim3(256), 0, stream>>>(partials, (float*)d_out);
}

// Round 7
// 125.184 us; speedup vs baseline: 1.1947x; 1.0821x over previous
//
#include <hip/hip_runtime.h>
#include <hip/hip_bf16.h>
#include <stdint.h>
#include <stddef.h>

#define NTOT 8192
#define BS   4096
#define DIM  1024
#define NTRI 2080   // 64*65/2 triangular tiles

// ws layout (bytes)
#define OFF_TB      0u          // bf16 total: 8192*1024*2 = 16777216
#define OFF_SQ      16777216u   // f32 [8192]
#define OFF_COLPART 16809984u   // f32 [128][1024]
#define OFF_BWP     17334272u   // f32 [8]
#define OFF_PART    17334336u   // f32 [NTRI]

typedef __attribute__((ext_vector_type(8))) short bf16x8;
typedef __attribute__((ext_vector_type(4))) float f32x4;

__device__ __forceinline__ unsigned short f2bf_rne(float f) {
  unsigned u = __float_as_uint(f);
  u += 0x7fffu + ((u >> 16) & 1u);
  return (unsigned short)(u >> 16);
}

__device__ __forceinline__ float bf2f(unsigned short h) {
  return __uint_as_float((unsigned)h << 16);
}

__device__ __forceinline__ float fast_sqrt(float x) {
#if __has_builtin(__builtin_amdgcn_sqrtf)
  return __builtin_amdgcn_sqrtf(x);
#else
  float r; asm("v_sqrt_f32 %0, %1" : "=v"(r) : "v"(x)); return r;
#endif
}

__device__ __forceinline__ float fast_exp2(float x) {
#if __has_builtin(__builtin_amdgcn_exp2f)
  return __builtin_amdgcn_exp2f(x);
#else
  float r; asm("v_exp_f32 %0, %1" : "=v"(r) : "v"(x)); return r;
#endif
}

__device__ __forceinline__ void load_lds16(const void* g, void* l) {
  __builtin_amdgcn_global_load_lds((const __attribute__((address_space(1))) void*)g,
                                   (__attribute__((address_space(3))) void*)l,
                                   16, 0, 0);
}

// ---- kernel A: bf16 convert + row sums of squares (16 rows/block) ----
__global__ __launch_bounds__(256) void prep_kernel(const float* __restrict__ src,
                                                   const float* __restrict__ tgt,
                                                   unsigned short* __restrict__ tb,
                                                   float* __restrict__ sq) {
  const int t = threadIdx.x;
  const int lane = t & 63, wave = t >> 6;
  const int r0 = blockIdx.x * 16;
  __shared__ float rs[16][4];
#pragma unroll 4
  for (int r = 0; r < 16; ++r) {
    const int row = r0 + r;
    const float* base = (row < BS) ? (src + (size_t)row * DIM)
                                   : (tgt + (size_t)(row - BS) * DIM);
    float4 v = *reinterpret_cast<const float4*>(base + t * 4);
    ushort4 b;
    b.x = f2bf_rne(v.x); b.y = f2bf_rne(v.y);
    b.z = f2bf_rne(v.z); b.w = f2bf_rne(v.w);
    *reinterpret_cast<ushort4*>(tb + (size_t)row * DIM + t * 4) = b;
    float s = v.x*v.x + v.y*v.y + v.z*v.z + v.w*v.w;
#pragma unroll
    for (int off = 32; off > 0; off >>= 1) s += __shfl_down(s, off, 64);
    if (lane == 0) rs[r][wave] = s;
  }
  __syncthreads();
  if (t < 16) sq[r0 + t] = (rs[t][0] + rs[t][1]) + (rs[t][2] + rs[t][3]);
}

// ---- kernel B: column-sum partials from the cache-hot bf16 copy ----
__global__ __launch_bounds__(256) void colsum_kernel(const unsigned short* __restrict__ tb,
                                                     float* __restrict__ colpart) {
  const int g = blockIdx.x;   // 128 blocks, 64 rows each
  const int t = threadIdx.x;  // 4 cols per thread
  float a0 = 0.f, a1 = 0.f, a2 = 0.f, a3 = 0.f;
  for (int r = 0; r < 64; ++r) {
    const int row = g * 64 + r;
    ushort4 u = *reinterpret_cast<const ushort4*>(tb + (size_t)row * DIM + t * 4);
    a0 += bf2f(u.x); a1 += bf2f(u.y); a2 += bf2f(u.z); a3 += bf2f(u.w);
  }
  float4 o = {a0, a1, a2, a3};
  *reinterpret_cast<float4*>(colpart + (size_t)g * 1024 + t * 4) = o;
}

// ---- kernel C: bandwidth from analytic sum(L2), 1024 threads (1 col/thread) ----
__global__ __launch_bounds__(1024) void bw_kernel(const float* __restrict__ sq,
                                                  const float* __restrict__ colpart,
                                                  float* __restrict__ bwp) {
  const int t = threadIdx.x;
  double s1 = 0.0;
#pragma unroll
  for (int i = 0; i < 8; ++i) s1 += (double)sq[t + i * 1024];
  float s = 0.f;
  for (int g = 0; g < 128; ++g) s += colpart[(size_t)g * 1024 + t];
  double s2 = (double)s * (double)s;
  __shared__ double r1[1024], r2[1024];
  r1[t] = s1; r2[t] = s2;
  __syncthreads();
  for (int off = 512; off > 0; off >>= 1) {
    if (t < off) { r1[t] += r1[t + off]; r2[t] += r2[t + off]; }
    __syncthreads();
  }
  if (t == 0) {
    const double n = (double)NTOT;
    double sumL2 = 2.0 * n * r1[0] - 2.0 * r2[0];
    double bw = sumL2 / (n * n - n);
    bw = bw / 4.0;  // KERNEL_MUL^(KERNEL_NUM//2) = 2^2
    const double LOG2E = 1.4426950408889634;
    for (int k = 0; k < 5; ++k)
      bwp[k] = (float)(-LOG2E / (bw * (double)(1 << k)));  // exp2-folded
  }
}

// stage one K=64 tile pair (A,B): 128 rows x 64 k = 1024 16B-chunks each.
// Linear LDS dest (gload_lds HW requirement); pre-swizzled global source:
// chunk f holds row f>>3, logical col-chunk (f&7)^((f>>3)&7) [involution].
// 8 vmcnt events per thread per call.
#define STAGE2(k0, ldsA, ldsB)                                                \
  do {                                                                        \
    _Pragma("unroll")                                                         \
    for (int l = 0; l < 4; ++l) {                                             \
      load_lds16(T + aoff[l] + (k0), (ldsA) + (size_t)(l * 256 + wave * 64) * 8); \
      load_lds16(T + boff[l] + (k0), (ldsB) + (size_t)(l * 256 + wave * 64) * 8); \
    }                                                                         \
  } while (0)

// one K=64 tile of MFMA from static buffers (swizzled ds_read addresses)
#define COMPUTE64(ldsA, ldsB)                                                 \
  do {                                                                        \
    _Pragma("unroll")                                                         \
    for (int kh = 0; kh < 2; ++kh) {                                          \
      const int kcc = kh ? kc1 : kc0;                                         \
      bf16x8 a[4], b[4];                                                      \
      _Pragma("unroll")                                                       \
      for (int m = 0; m < 4; ++m)                                             \
        a[m] = *reinterpret_cast<const bf16x8*>(                              \
            &(ldsA)[(wr * 64 + m * 16 + r15) * 64 + kcc * 8]);                \
      _Pragma("unroll")                                                       \
      for (int n = 0; n < 4; ++n)                                             \
        b[n] = *reinterpret_cast<const bf16x8*>(                              \
            &(ldsB)[(wc * 64 + n * 16 + r15) * 64 + kcc * 8]);                \
      _Pragma("unroll")                                                       \
      for (int m = 0; m < 4; ++m)                                             \
        _Pragma("unroll")                                                     \
        for (int n = 0; n < 4; ++n)                                           \
          acc[m][n] = __builtin_amdgcn_mfma_f32_16x16x32_bf16(a[m], b[n],     \
                                                              acc[m][n], 0, 0, 0); \
    }                                                                         \
  } while (0)

// ---- kernel D: fused bf16 Gram GEMM + RBF epilogue, upper-triangular tiles ----
// 128x128 tile, BK=64, 4 waves (2x2), double-buffered with COUNTED vmcnt:
// per K-tile { issue next tile's 8 gload_lds; s_waitcnt vmcnt(8) (retires the
// PREVIOUS tile's loads, leaves new 8 in flight under MFMA); s_barrier;
// ds_read+MFMA; s_barrier }. No vmcnt(0) drain in the main loop (T4).
// Race proof: stage(bufX) is issued only after a barrier at which all waves'
// ds_reads of bufX were consumed (MFMA data-dependence); compute(bufX) follows
// a barrier at which every wave vmcnt-confirmed bufX's loads landed.
__global__ __launch_bounds__(256, 2) void mmd_gemm(const short* __restrict__ T,
                                                   const float* __restrict__ sq,
                                                   const float* __restrict__ bwp,
                                                   float* __restrict__ partials) {
  __shared__ __align__(16) short sA0[128 * 64], sA1[128 * 64];
  __shared__ __align__(16) short sB0[128 * 64], sB1[128 * 64];
  __shared__ float wred[4];

  const int tid  = threadIdx.x;
  const int lane = tid & 63;
  const int wave = tid >> 6;       // 0..3
  const int wr   = wave >> 1;      // wave row (0..1)
  const int wc   = wave & 1;       // wave col (0..1)

  // XCD-aware chunked swizzle: 8 XCDs x 260 contiguous triangular tiles
  const int tno = (blockIdx.x & 7) * 260 + (blockIdx.x >> 3);
  // triangular decode: tile tno -> (bi, bj) with bi<=bj, f(bi)=bi*(129-bi)/2
  int bi = (int)((129.0f - fast_sqrt(129.0f * 129.0f - 8.0f * (float)tno)) * 0.5f);
  while (bi > 0 && bi * (129 - bi) / 2 > tno) --bi;
  while ((bi + 1) * (129 - (bi + 1)) / 2 <= tno) ++bi;
  const int bj = bi + (tno - bi * (129 - bi) / 2);

  const size_t arow = (size_t)bi * 128;
  const size_t brow = (size_t)bj * 128;

  // precompute the 8 staging source offsets (k0-independent parts)
  int aoff[4], boff[4];
#pragma unroll
  for (int l = 0; l < 4; ++l) {
    const int f = l * 256 + tid;
    const int cs = ((f & 7) ^ ((f >> 3) & 7)) * 8;
    aoff[l] = (int)((arow + (f >> 3)) * DIM) + cs;
    boff[l] = (int)((brow + (f >> 3)) * DIM) + cs;
  }

  f32x4 acc[4][4] = {};

  const int r15 = lane & 15;
  const int kg  = lane >> 4;                   // 0..3
  const int kc0 = kg ^ (r15 & 7);              // swizzled chunk, k-half 0
  const int kc1 = (4 + kg) ^ (r15 & 7);        // swizzled chunk, k-half 1

  // prologue: stage K-tile 0 (8 loads in flight)
  STAGE2(0, sA0, sB0);

  for (int tt = 0; tt < 8; ++tt) {
    // even K-tile 2tt in buf0; stage odd K-tile 2tt+1 into buf1
    STAGE2((2 * tt + 1) * 64, sA1, sB1);
    asm volatile("s_waitcnt vmcnt(8)" ::: "memory");   // tile-2tt loads landed
    __builtin_amdgcn_s_barrier();
    __builtin_amdgcn_sched_barrier(0);
    COMPUTE64(sA0, sB0);
    __builtin_amdgcn_sched_barrier(0);
    __builtin_amdgcn_s_barrier();                      // buf0 reads done everywhere

    // odd K-tile 2tt+1 in buf1; stage even K-tile 2tt+2 into buf0
    if (tt < 7) {
      STAGE2((2 * tt + 2) * 64, sA0, sB0);
      asm volatile("s_waitcnt vmcnt(8)" ::: "memory"); // tile-2tt+1 loads landed
    } else {
      asm volatile("s_waitcnt vmcnt(0)" ::: "memory"); // last tile: drain
    }
    __builtin_amdgcn_s_barrier();
    __builtin_amdgcn_sched_barrier(0);
    COMPUTE64(sA1, sB1);
    __builtin_amdgcn_sched_barrier(0);
    __builtin_amdgcn_s_barrier();                      // buf1 reads done everywhere
  }

  // epilogue: x = l2 * ni0 in exp2 domain; u = 2^(x/16);
  // sum_k exp2(x/2^k) = u + u^2 + u^4 + u^8 + u^16  (1 trans op total)
  const float s16 = bwp[0] * 0.0625f;  // -log2e/(16*bw)
  const float c2  = -2.f * s16;
  const int hi = lane >> 4;

  float ai[4][4];
#pragma unroll
  for (int m = 0; m < 4; ++m)
#pragma unroll
    for (int r = 0; r < 4; ++r)
      ai[m][r] = sq[bi * 128 + wr * 64 + m * 16 + hi * 4 + r] * s16;

  float tsum = 0.f;
#pragma unroll
  for (int n = 0; n < 4; ++n) {
    const float bjv = sq[bj * 128 + wc * 64 + n * 16 + r15] * s16;
#pragma unroll
    for (int m = 0; m < 4; ++m) {
#pragma unroll
      for (int r = 0; r < 4; ++r) {
        float x16 = fmaf(acc[m][n][r], c2, ai[m][r] + bjv);  // in [-0.9, 0]
        float u   = fast_exp2(x16);
        float u2 = u * u, u4 = u2 * u2, u8 = u4 * u4, u16 = u8 * u8;
        tsum += ((u + u2) + (u4 + u8)) + u16;
      }
    }
  }

#pragma unroll
  for (int off = 32; off > 0; off >>= 1) tsum += __shfl_down(tsum, off, 64);
  if (lane == 0) wred[wave] = tsum;
  __syncthreads();
  if (tid == 0) {
    float sign = ((bi < 32) == (bj < 32)) ? 1.f : -1.f;
    float wgt  = (bi == bj) ? 1.f : 2.f;
    partials[tno] = sign * wgt * ((wred[0] + wred[1]) + (wred[2] + wred[3]));
  }
}

// ---- kernel E: final reduction ----
__global__ __launch_bounds__(256) void finish_kernel(const float* __restrict__ partials,
                                                     float* __restrict__ out) {
  const int t = threadIdx.x;
  double s = 0.0;
  for (int i = t; i < NTRI; i += 256) s += (double)partials[i];
  __shared__ double rd[256];
  rd[t] = s;
  __syncthreads();
  for (int off = 128; off > 0; off >>= 1) {
    if (t < off) rd[t] += rd[t + off];
    __syncthreads();
  }
  if (t == 0) out[0] = (float)(rd[0] / 16777216.0);  // / bs^2
}

extern "C" void kernel_launch(void* const* d_in, const int* in_sizes, int n_in,
                              void* d_out, int out_size, void* d_ws, size_t ws_size,
                              hipStream_t stream) {
  const float* src = (const float*)d_in[0];
  const float* tgt = (const float*)d_in[1];
  char* ws = (char*)d_ws;
  unsigned short* tb = (unsigned short*)(ws + OFF_TB);
  float* sq       = (float*)(ws + OFF_SQ);
  float* colpart  = (float*)(ws + OFF_COLPART);
  float* bwp      = (float*)(ws + OFF_BWP);
  float* partials = (float*)(ws + OFF_PART);

  prep_kernel<<<dim3(512), dim3(256), 0, stream>>>(src, tgt, tb, sq);
  colsum_kernel<<<dim3(128), dim3(256), 0, stream>>>(tb, colpart);
  bw_kernel<<<dim3(1), dim3(1024), 0, stream>>>(sq, colpart, bwp);
  mmd_gemm<<<dim3(NTRI), dim3(256), 0, stream>>>((const short*)tb, sq, bwp, partials);
  finish_kernel<<<dim3(1), dim3(256), 0, stream>>>(partials, (float*)d_out);
}